// Round 1
// baseline (156.943 us; speedup 1.0000x reference)
//
#include <hip/hip_runtime.h>

typedef float float4v __attribute__((ext_vector_type(4)));

#define DIM 128

__device__ __forceinline__ int f2i_ord(float f) {
    int b = __float_as_int(f);
    return b >= 0 ? b : (b ^ 0x7FFFFFFF);
}

// f2i_ord(-inf) = 0xFF800000 ^ 0x7FFFFFFF = 0x807FFFFF
#define NEG_INF_ORD ((int)0x807FFFFF)

__global__ void init_out_kernel(int* __restrict__ out, int n) {
    int i = blockIdx.x * blockDim.x + threadIdx.x;
    if (i < n) out[i] = NEG_INF_ORD;
}

__global__ void finalize_out_kernel(int* __restrict__ out, int n) {
    int i = blockIdx.x * blockDim.x + threadIdx.x;
    if (i < n) {
        int b = out[i];
        b = (b >= 0) ? b : (b ^ 0x7FFFFFFF);
        ((float*)out)[i] = __int_as_float(b);
    }
}

__global__ __launch_bounds__(256) void segmax_kernel(
    const float* __restrict__ x, const int* __restrict__ batch,
    int* __restrict__ out, int N, int rows_per_group, int ngroups)
{
    int gtid = blockIdx.x * blockDim.x + threadIdx.x;
    int wave = gtid >> 6;
    int lane = threadIdx.x & 63;
    if (wave >= ngroups) return;

    int r0 = wave * rows_per_group;
    if (r0 >= N) return;
    int r1 = min(r0 + rows_per_group, N);

    int half = lane >> 5;          // 0 or 1: which row of the pair
    int c = (lane & 31) * 4;       // column offset (float4 per lane)

    float4v acc;
    acc.x = -INFINITY; acc.y = -INFINITY; acc.z = -INFINITY; acc.w = -INFINITY;
    int cur = -1;

    for (int r = r0 + half; r < r1; r += 2) {
        int seg = batch[r];
        if (seg != cur) {
            if (cur >= 0) {
                int* o = out + (size_t)cur * DIM + c;
                atomicMax(o + 0, f2i_ord(acc.x));
                atomicMax(o + 1, f2i_ord(acc.y));
                atomicMax(o + 2, f2i_ord(acc.z));
                atomicMax(o + 3, f2i_ord(acc.w));
                acc.x = -INFINITY; acc.y = -INFINITY;
                acc.z = -INFINITY; acc.w = -INFINITY;
            }
            cur = seg;
        }
        const float4v v = *(const float4v*)(x + (size_t)r * DIM + c);
        acc.x = fmaxf(acc.x, v.x);
        acc.y = fmaxf(acc.y, v.y);
        acc.z = fmaxf(acc.z, v.z);
        acc.w = fmaxf(acc.w, v.w);
    }
    if (cur >= 0) {
        int* o = out + (size_t)cur * DIM + c;
        atomicMax(o + 0, f2i_ord(acc.x));
        atomicMax(o + 1, f2i_ord(acc.y));
        atomicMax(o + 2, f2i_ord(acc.z));
        atomicMax(o + 3, f2i_ord(acc.w));
    }
}

extern "C" void kernel_launch(void* const* d_in, const int* in_sizes, int n_in,
                              void* d_out, int out_size, void* d_ws, size_t ws_size,
                              hipStream_t stream) {
    const float* x = (const float*)d_in[0];
    const int* batch = (const int*)d_in[1];
    int* out = (int*)d_out;

    int N = in_sizes[1];              // number of rows (batch has N entries)
    int n_out = out_size;             // G * 128

    // Phase 1: init output to encoded -inf
    {
        int threads = 256;
        int blocks = (n_out + threads - 1) / threads;
        init_out_kernel<<<blocks, threads, 0, stream>>>(out, n_out);
    }

    // Phase 2: segment-max scan. 4096 waves, each owns a contiguous row range.
    {
        int ngroups = 4096;                          // waves
        int rows_per_group = (N + ngroups - 1) / ngroups;
        int blocks = (ngroups + 3) / 4;              // 4 waves per 256-thread block
        segmax_kernel<<<blocks, 256, 0, stream>>>(x, batch, out, N, rows_per_group, ngroups);
    }

    // Phase 3: decode ordered-int back to float (in place)
    {
        int threads = 256;
        int blocks = (n_out + threads - 1) / threads;
        finalize_out_kernel<<<blocks, threads, 0, stream>>>(out, n_out);
    }
}

// Round 2
// 117.028 us; speedup vs baseline: 1.3411x; 1.3411x over previous
//
#include <hip/hip_runtime.h>

typedef float float4v __attribute__((ext_vector_type(4)));

#define DIM 128

__device__ __forceinline__ int f2i_ord(float f) {
    int b = __float_as_int(f);
    return b >= 0 ? b : (b ^ 0x7FFFFFFF);
}

// f2i_ord(-inf) = 0xFF800000 ^ 0x7FFFFFFF = 0x807FFFFF
#define NEG_INF_ORD ((int)0x807FFFFF)

__global__ void init_out_kernel(int* __restrict__ out, int n) {
    int i = blockIdx.x * blockDim.x + threadIdx.x;
    if (i < n) out[i] = NEG_INF_ORD;
}

__global__ void finalize_out_kernel(int* __restrict__ out, int n) {
    int i = blockIdx.x * blockDim.x + threadIdx.x;
    if (i < n) {
        int b = out[i];
        b = (b >= 0) ? b : (b ^ 0x7FFFFFFF);
        ((float*)out)[i] = __int_as_float(b);
    }
}

__device__ __forceinline__ void flush_seg(int* __restrict__ out, int cur, int c,
                                          const float4v& acc) {
    int* o = out + (size_t)cur * DIM + c;
    atomicMax(o + 0, f2i_ord(acc.x));
    atomicMax(o + 1, f2i_ord(acc.y));
    atomicMax(o + 2, f2i_ord(acc.z));
    atomicMax(o + 3, f2i_ord(acc.w));
}

__device__ __forceinline__ void acc_max(float4v& acc, const float4v& v) {
    acc.x = fmaxf(acc.x, v.x);
    acc.y = fmaxf(acc.y, v.y);
    acc.z = fmaxf(acc.z, v.z);
    acc.w = fmaxf(acc.w, v.w);
}

__global__ __launch_bounds__(256) void segmax_kernel(
    const float* __restrict__ x, const int* __restrict__ batch,
    int* __restrict__ out, int N, int rows_per_group, int ngroups)
{
    int gtid = blockIdx.x * blockDim.x + threadIdx.x;
    int wave = gtid >> 6;
    int lane = threadIdx.x & 63;
    if (wave >= ngroups) return;

    int r0 = wave * rows_per_group;
    if (r0 >= N) return;
    int r1 = min(r0 + rows_per_group, N);

    int half = lane >> 5;          // 0 or 1: which row of the pair
    int c = (lane & 31) * 4;       // column offset (float4 per lane)

    float4v acc;
    acc.x = -INFINITY; acc.y = -INFINITY; acc.z = -INFINITY; acc.w = -INFINITY;
    int cur = -1;

    int r = r0 + half;

#define PROCESS(S, V)                                              \
    do {                                                           \
        if ((S) != cur) {                                          \
            if (cur >= 0) flush_seg(out, cur, c, acc);             \
            acc.x = -INFINITY; acc.y = -INFINITY;                  \
            acc.z = -INFINITY; acc.w = -INFINITY;                  \
            cur = (S);                                             \
        }                                                          \
        acc_max(acc, (V));                                         \
    } while (0)

    // Main loop: 4 row-pairs (8 rows) per iteration. Issue all loads first
    // so 4 vector loads are in flight before any data-dependent branch.
    for (; r + 6 < r1; r += 8) {
        int s0 = batch[r];
        int s1 = batch[r + 2];
        int s2 = batch[r + 4];
        int s3 = batch[r + 6];
        float4v v0 = *(const float4v*)(x + (size_t)r * DIM + c);
        float4v v1 = *(const float4v*)(x + (size_t)(r + 2) * DIM + c);
        float4v v2 = *(const float4v*)(x + (size_t)(r + 4) * DIM + c);
        float4v v3 = *(const float4v*)(x + (size_t)(r + 6) * DIM + c);
        // batch sorted ascending: s0==cur && s3==cur  =>  s1==s2==cur
        if (s0 == cur && s3 == cur) {
            acc_max(acc, v0);
            acc_max(acc, v1);
            acc_max(acc, v2);
            acc_max(acc, v3);
        } else {
            PROCESS(s0, v0);
            PROCESS(s1, v1);
            PROCESS(s2, v2);
            PROCESS(s3, v3);
        }
    }
    // Tail
    for (; r < r1; r += 2) {
        int seg = batch[r];
        float4v v = *(const float4v*)(x + (size_t)r * DIM + c);
        PROCESS(seg, v);
    }
#undef PROCESS

    if (cur >= 0) flush_seg(out, cur, c, acc);
}

extern "C" void kernel_launch(void* const* d_in, const int* in_sizes, int n_in,
                              void* d_out, int out_size, void* d_ws, size_t ws_size,
                              hipStream_t stream) {
    const float* x = (const float*)d_in[0];
    const int* batch = (const int*)d_in[1];
    int* out = (int*)d_out;

    int N = in_sizes[1];              // number of rows (batch has N entries)
    int n_out = out_size;             // G * 128

    // Phase 1: init output to encoded -inf
    {
        int threads = 256;
        int blocks = (n_out + threads - 1) / threads;
        init_out_kernel<<<blocks, threads, 0, stream>>>(out, n_out);
    }

    // Phase 2: segment-max scan. 8192 waves (2048 blocks) = 32 waves/CU.
    {
        int ngroups = 8192;
        int rows_per_group = (N + ngroups - 1) / ngroups;
        int blocks = (ngroups + 3) / 4;              // 4 waves per 256-thread block
        segmax_kernel<<<blocks, 256, 0, stream>>>(x, batch, out, N, rows_per_group, ngroups);
    }

    // Phase 3: decode ordered-int back to float (in place)
    {
        int threads = 256;
        int blocks = (n_out + threads - 1) / threads;
        finalize_out_kernel<<<blocks, threads, 0, stream>>>(out, n_out);
    }
}

// Round 3
// 100.466 us; speedup vs baseline: 1.5622x; 1.1649x over previous
//
#include <hip/hip_runtime.h>

typedef float float4v __attribute__((ext_vector_type(4)));

#define DIM 128

// Kernel 1: starts[g] = first row index i with batch[i] >= g  (batch sorted).
// Also starts[G] = N. Covers empty segments (runs of missing g values).
__global__ __launch_bounds__(256) void find_starts_kernel(
    const int* __restrict__ batch, int* __restrict__ starts, int N, int G)
{
    int i = blockIdx.x * blockDim.x + threadIdx.x;
    if (i >= N) return;
    int b = batch[i];
    int prev = (i == 0) ? -1 : batch[i - 1];
    for (int g = prev + 1; g <= b; ++g) starts[g] = i;
    if (i == N - 1) {
        for (int g = b + 1; g <= G; ++g) starts[g] = N;
    }
}

// Kernel 2: one wave per segment. Branch-free streaming max, direct f32 store.
__global__ __launch_bounds__(256) void segmax_direct_kernel(
    const float* __restrict__ x, const int* __restrict__ starts,
    float* __restrict__ out, int G)
{
    int gtid = blockIdx.x * blockDim.x + threadIdx.x;
    int seg = gtid >> 6;
    int lane = threadIdx.x & 63;
    if (seg >= G) return;

    int r0 = starts[seg];
    int r1 = starts[seg + 1];

    int half = lane >> 5;          // which row of a pair this half-wave takes
    int c = (lane & 31) * 4;       // column offset (float4 per lane)

    float4v acc;
    acc.x = -INFINITY; acc.y = -INFINITY; acc.z = -INFINITY; acc.w = -INFINITY;

    const float* xc = x + c;
    int r = r0 + half;

    // 8 rows (4 per half-wave) per iteration; all loads issued before use.
    for (; r + 6 < r1; r += 8) {
        float4v v0 = *(const float4v*)(xc + (size_t)r * DIM);
        float4v v1 = *(const float4v*)(xc + (size_t)(r + 2) * DIM);
        float4v v2 = *(const float4v*)(xc + (size_t)(r + 4) * DIM);
        float4v v3 = *(const float4v*)(xc + (size_t)(r + 6) * DIM);
        acc.x = fmaxf(fmaxf(acc.x, v0.x), fmaxf(v1.x, v2.x));
        acc.y = fmaxf(fmaxf(acc.y, v0.y), fmaxf(v1.y, v2.y));
        acc.z = fmaxf(fmaxf(acc.z, v0.z), fmaxf(v1.z, v2.z));
        acc.w = fmaxf(fmaxf(acc.w, v0.w), fmaxf(v1.w, v2.w));
        acc.x = fmaxf(acc.x, v3.x);
        acc.y = fmaxf(acc.y, v3.y);
        acc.z = fmaxf(acc.z, v3.z);
        acc.w = fmaxf(acc.w, v3.w);
    }
    for (; r < r1; r += 2) {
        float4v v = *(const float4v*)(xc + (size_t)r * DIM);
        acc.x = fmaxf(acc.x, v.x);
        acc.y = fmaxf(acc.y, v.y);
        acc.z = fmaxf(acc.z, v.z);
        acc.w = fmaxf(acc.w, v.w);
    }

    // Combine the two half-wave partials (even rows vs odd rows).
    acc.x = fmaxf(acc.x, __shfl_xor(acc.x, 32));
    acc.y = fmaxf(acc.y, __shfl_xor(acc.y, 32));
    acc.z = fmaxf(acc.z, __shfl_xor(acc.z, 32));
    acc.w = fmaxf(acc.w, __shfl_xor(acc.w, 32));

    if (half == 0) {
        *(float4v*)(out + (size_t)seg * DIM + c) = acc;
    }
}

extern "C" void kernel_launch(void* const* d_in, const int* in_sizes, int n_in,
                              void* d_out, int out_size, void* d_ws, size_t ws_size,
                              hipStream_t stream) {
    const float* x = (const float*)d_in[0];
    const int* batch = (const int*)d_in[1];
    float* out = (float*)d_out;

    int N = in_sizes[1];              // number of rows
    int G = out_size / DIM;           // number of segments

    int* starts = (int*)d_ws;         // G+1 ints

    // Phase 1: segment boundary discovery.
    {
        int threads = 256;
        int blocks = (N + threads - 1) / threads;
        find_starts_kernel<<<blocks, threads, 0, stream>>>(batch, starts, N, G);
    }

    // Phase 2: one wave per segment, branch-free streaming max, direct store.
    {
        int waves = G;
        int blocks = (waves * 64 + 255) / 256;
        segmax_direct_kernel<<<blocks, 256, 0, stream>>>(x, starts, out, G);
    }
}